// Round 5
// baseline (4061.019 us; speedup 1.0000x reference)
//
#include <hip/hip_runtime.h>
#include <hip/hip_bf16.h>
#include <math.h>

// PPOActorRNN on MI355X — round 5: R4 structure + fixed grid barrier.
// R4 post-mortem: single-cacheline barrier w/ s_sleep(1) polling saturated the
// coherence point (MfmaUtil 1.7%, all pipes idle). R5: two-level arrival
// (16 sub-counters -> master -> gen), s_sleep(64) backoff polling, grid=512.

#define TTT 256
#define BBB 256
#define DDD 512
#define ACT 32
#define MMM (TTT*BBB)
#define NBLK 512          // 2 blocks/CU guaranteed by __launch_bounds__(256,2)

typedef short bf16x8 __attribute__((ext_vector_type(8)));
typedef float f32x4 __attribute__((ext_vector_type(4)));
typedef unsigned short u16;

__device__ inline u16 f2bf(float f) {
    unsigned int u = __float_as_uint(f);
    u += 0x7fffu + ((u >> 16) & 1u);
    return (u16)(u >> 16);
}
__device__ inline float bf2f(u16 h) { return __uint_as_float(((unsigned int)h) << 16); }

// ---------------- transpose + cvt: out[n*ostride + k] = bf16(in[k*512 + n]) ----
__global__ __launch_bounds__(256) void transpose_cvt_k(
    const float* __restrict__ in, u16* __restrict__ out, int ostride)
{
    __shared__ float tile[32][33];
    const int c = threadIdx.x & 31;
    const int r0 = threadIdx.x >> 5;
    const int bx = blockIdx.x, by = blockIdx.y;
#pragma unroll
    for (int p = 0; p < 4; p++) {
        int r = r0 + p * 8;
        tile[r][c] = in[(size_t)(by * 32 + r) * DDD + bx * 32 + c];
    }
    __syncthreads();
#pragma unroll
    for (int p = 0; p < 4; p++) {
        int r = r0 + p * 8;
        out[(size_t)(bx * 32 + r) * ostride + by * 32 + c] = f2bf(tile[c][r]);
    }
}

// ---------------- MFMA GEMM (parallel phases) ----------------
template<bool AF32>
__global__ __launch_bounds__(256) void gemm_bf16_k(
    const void* __restrict__ Aptr, const u16* __restrict__ Bt,
    const float* __restrict__ bias, u16* __restrict__ C, int N)
{
    __shared__ u16 As[128 * 64];
    __shared__ u16 Bs[128 * 64];
    const int tid = threadIdx.x;
    const int row0 = blockIdx.x * 128;
    const int col0 = blockIdx.y * 128;
    const int lane = tid & 63, wid = tid >> 6;
    const int wr = wid >> 1, wc = wid & 1;
    const int lm = lane & 15, lq = lane >> 4;

    f32x4 acc[4][4];
#pragma unroll
    for (int i = 0; i < 4; i++)
#pragma unroll
        for (int j = 0; j < 4; j++) acc[i][j] = (f32x4){0.f, 0.f, 0.f, 0.f};

    for (int kc = 0; kc < 8; kc++) {
        const int k0 = kc * 64;
#pragma unroll
        for (int p = 0; p < 4; p++) {
            int g = p * 256 + tid;
            int row = g >> 3, j = g & 7;
            bf16x8 v;
            if (AF32) {
                const float* s = (const float*)Aptr + (size_t)(row0 + row) * DDD + k0 + j * 8;
                float4 a0 = *(const float4*)s;
                float4 a1 = *(const float4*)(s + 4);
                v[0] = (short)f2bf(a0.x); v[1] = (short)f2bf(a0.y);
                v[2] = (short)f2bf(a0.z); v[3] = (short)f2bf(a0.w);
                v[4] = (short)f2bf(a1.x); v[5] = (short)f2bf(a1.y);
                v[6] = (short)f2bf(a1.z); v[7] = (short)f2bf(a1.w);
            } else {
                v = *(const bf16x8*)((const u16*)Aptr + (size_t)(row0 + row) * DDD + k0 + j * 8);
            }
            *(bf16x8*)(As + row * 64 + ((j ^ (row & 7)) << 3)) = v;
        }
#pragma unroll
        for (int p = 0; p < 4; p++) {
            int g = p * 256 + tid;
            int n = g >> 3, j = g & 7;
            bf16x8 v = *(const bf16x8*)(Bt + (size_t)(col0 + n) * DDD + k0 + j * 8);
            *(bf16x8*)(Bs + n * 64 + ((j ^ (n & 7)) << 3)) = v;
        }
        __syncthreads();
#pragma unroll
        for (int ks = 0; ks < 2; ks++) {
            bf16x8 af[4], bfr[4];
#pragma unroll
            for (int i = 0; i < 4; i++) {
                int row = wr * 64 + i * 16 + lm;
                af[i] = *(const bf16x8*)(As + row * 64 + (((ks * 4 + lq) ^ (row & 7)) << 3));
            }
#pragma unroll
            for (int j = 0; j < 4; j++) {
                int n = wc * 64 + j * 16 + lm;
                bfr[j] = *(const bf16x8*)(Bs + n * 64 + (((ks * 4 + lq) ^ (n & 7)) << 3));
            }
#pragma unroll
            for (int i = 0; i < 4; i++)
#pragma unroll
                for (int j = 0; j < 4; j++)
                    acc[i][j] = __builtin_amdgcn_mfma_f32_16x16x32_bf16(af[i], bfr[j], acc[i][j], 0, 0, 0);
        }
        __syncthreads();
    }
#pragma unroll
    for (int j = 0; j < 4; j++) {
        int col = col0 + wc * 64 + j * 16 + lm;
        float bj = bias[col];
#pragma unroll
        for (int i = 0; i < 4; i++) {
            int rb = row0 + wr * 64 + i * 16 + lq * 4;
#pragma unroll
            for (int r = 0; r < 4; r++)
                C[(size_t)(rb + r) * N + col] = f2bf(acc[i][j][r] + bj);
        }
    }
}

// ---------------- LayerNorm + ReLU in-place on bf16 [M x 512] ----------------
__global__ __launch_bounds__(256) void ln_relu_k(
    u16* __restrict__ X, const float* __restrict__ gamma, const float* __restrict__ beta)
{
    const int tid = threadIdx.x;
    const int lane = tid & 63;
    const size_t row = (size_t)blockIdx.x * 4 + (tid >> 6);
    const int c0 = lane * 8;
    u16* px = X + row * DDD + c0;
    bf16x8 v = *(const bf16x8*)px;
    float f[8]; float s = 0.f, s2 = 0.f;
#pragma unroll
    for (int i = 0; i < 8; i++) { f[i] = bf2f((u16)v[i]); s += f[i]; s2 += f[i] * f[i]; }
#pragma unroll
    for (int off = 32; off; off >>= 1) { s += __shfl_xor(s, off); s2 += __shfl_xor(s2, off); }
    float mu = s * (1.f / (float)DDD);
    float rs = rsqrtf(s2 * (1.f / (float)DDD) - mu * mu + 1e-6f);
    float4 g0 = *(const float4*)(gamma + c0), g1 = *(const float4*)(gamma + c0 + 4);
    float4 b0 = *(const float4*)(beta + c0),  b1 = *(const float4*)(beta + c0 + 4);
    float gg[8] = {g0.x, g0.y, g0.z, g0.w, g1.x, g1.y, g1.z, g1.w};
    float bb[8] = {b0.x, b0.y, b0.z, b0.w, b1.x, b1.y, b1.z, b1.w};
    bf16x8 o;
#pragma unroll
    for (int i = 0; i < 8; i++) {
        float yv = (f[i] - mu) * rs * gg[i] + bb[i];
        o[i] = (short)f2bf(fmaxf(yv, 0.f));
    }
    *(bf16x8*)px = o;
}

// ---------------- logits ----------------
__global__ __launch_bounds__(256) void logits_k(
    const u16* __restrict__ AM, const float* __restrict__ Wa,
    const float* __restrict__ ba, const int* __restrict__ avail,
    float* __restrict__ out)
{
    __shared__ float xs[8][DDD];
    const int tid = threadIdx.x;
    const size_t row0 = (size_t)blockIdx.x * 8;
    for (int g = tid; g < 8 * 64; g += 256) {
        int r = g >> 6, c8 = (g & 63) * 8;
        bf16x8 v = *(const bf16x8*)(AM + (row0 + r) * DDD + c8);
#pragma unroll
        for (int i = 0; i < 8; i++) xs[r][c8 + i] = bf2f((u16)v[i]);
    }
    __syncthreads();
    const int r = tid >> 5, a = tid & 31;
    float acc = 0.f;
    for (int k = 0; k < DDD; k += 4) {
        float4 xv = *(const float4*)&xs[r][k];
        acc = fmaf(xv.x, Wa[(k + 0) * ACT + a], acc);
        acc = fmaf(xv.y, Wa[(k + 1) * ACT + a], acc);
        acc = fmaf(xv.z, Wa[(k + 2) * ACT + a], acc);
        acc = fmaf(xv.w, Wa[(k + 3) * ACT + a], acc);
    }
    size_t o = (row0 + r) * ACT + a;
    float v = acc + ba[a];
    if (avail[o] == 0) v -= 1e10f;
    out[o] = v;
}

// ---------------- list building ----------------
__global__ __launch_bounds__(256) void depth_build_k(
    const int* __restrict__ dones,
    int* __restrict__ depthA, int* __restrict__ pidxA,
    int* __restrict__ counts, int* __restrict__ maxd)
{
    __shared__ int lc[256];
    __shared__ int lmax;
    const int b = threadIdx.x;
    lc[b] = 0;
    if (b == 0) lmax = 0;
    __syncthreads();
    int dprev = 0, mx = 0;
    for (int t = 0; t < TTT; t++) {
        int pos = t * BBB + b;
        int d, pi;
        if (dones[pos] != 0)       { d = 0; pi = -1; }
        else if (t == 0)           { d = 0; pi = -2 - b; }
        else                       { d = dprev + 1; pi = pos - BBB; }
        depthA[pos] = d; pidxA[pos] = pi;
        atomicAdd(&lc[d], 1);
        mx = max(mx, d);
        dprev = d;
    }
    atomicMax(&lmax, mx);
    __syncthreads();
    counts[b] = lc[b];
    if (b == 0) *maxd = lmax;
}

__global__ void scan_k(const int* __restrict__ counts, int* __restrict__ offs)
{
    if (threadIdx.x == 0) {
        int s = 0;
        for (int i = 0; i < 256; i++) { offs[i] = s; s += counts[i]; }
    }
}

__global__ __launch_bounds__(256) void scatter_k(
    const int* __restrict__ depthA, const int* __restrict__ offs,
    int* __restrict__ cursor, int* __restrict__ list)
{
    __shared__ int lcnt[256];
    __shared__ int lbase[256];
    const int tid = threadIdx.x;
    lcnt[tid] = 0;
    __syncthreads();
    int pos = blockIdx.x * 256 + tid;
    int d = depthA[pos];
    int rank = atomicAdd(&lcnt[d], 1);
    __syncthreads();
    int c = lcnt[tid];
    lbase[tid] = c ? atomicAdd(&cursor[tid], c) : 0;
    __syncthreads();
    list[offs[d] + lbase[d] + rank] = pos;
}

// ---------------- two-level grid barrier ----------------
// bar layout (ints): sub[16] at stride 32 (128B apart), master at 512, gen at 544.
__device__ inline void grid_barrier(int* __restrict__ bar)
{
    __syncthreads();
    if (threadIdx.x == 0) {
        __threadfence();   // publish Y writes device-wide
        int* gen = bar + 544;
        int g = __hip_atomic_load(gen, __ATOMIC_ACQUIRE, __HIP_MEMORY_SCOPE_AGENT);
        int grp = blockIdx.x & 15;
        int* cnt = bar + grp * 32;
        int a = __hip_atomic_fetch_add(cnt, 1, __ATOMIC_ACQ_REL, __HIP_MEMORY_SCOPE_AGENT);
        if (a == (NBLK / 16) - 1) {
            __hip_atomic_store(cnt, 0, __ATOMIC_RELAXED, __HIP_MEMORY_SCOPE_AGENT);
            int* master = bar + 512;
            int m = __hip_atomic_fetch_add(master, 1, __ATOMIC_ACQ_REL, __HIP_MEMORY_SCOPE_AGENT);
            if (m == 15) {
                __hip_atomic_store(master, 0, __ATOMIC_RELAXED, __HIP_MEMORY_SCOPE_AGENT);
                __hip_atomic_store(gen, g + 1, __ATOMIC_RELEASE, __HIP_MEMORY_SCOPE_AGENT);
            }
        }
        // backoff polling: 2 fast polls, then ~1.7 us sleeps
        if (__hip_atomic_load(gen, __ATOMIC_ACQUIRE, __HIP_MEMORY_SCOPE_AGENT) == g) {
            __builtin_amdgcn_s_sleep(2);
            while (__hip_atomic_load(gen, __ATOMIC_ACQUIRE, __HIP_MEMORY_SCOPE_AGENT) == g)
                __builtin_amdgcn_s_sleep(64);
        }
        __threadfence();
    }
    __syncthreads();
}

// ---------------- coop depth-scheduled GRU (structure identical to R4) ----------
template<bool YF32>
__global__ __launch_bounds__(256, 2) void gru_depth_k(
    const u16* __restrict__ E, const float* __restrict__ hidden,
    const u16* __restrict__ Wstk, const float* __restrict__ bi,
    const float* __restrict__ bhn,
    const int* __restrict__ list, const int* __restrict__ offs,
    const int* __restrict__ counts, const int* __restrict__ maxd,
    const int* __restrict__ pidxA,
    void* __restrict__ Yv, float* __restrict__ hid_out,
    int* __restrict__ bar)
{
    __shared__ u16 As[32 * 256];
    __shared__ int posL[32], pidxL[32];
    __shared__ int sAnyH;
    const int tid = threadIdx.x;
    const int w = tid >> 6, lane = tid & 63;
    const int lm = lane & 15, lq = lane >> 4;

    const int MD = *maxd;
    for (int d = 0; d <= MD; d++) {
        const int nd = counts[d];
        const int off = offs[d];
        const int njobs = ((nd + 31) >> 5) << 2;
        for (int j = blockIdx.x; j < njobs; j += NBLK) {
            const int rt = j >> 2, panel = j & 3;
            bool hasH = false;
            if (tid < 32) {
                int idx = rt * 32 + tid;
                int p = (idx < nd) ? list[off + idx] : -1;
                int pi = (p >= 0) ? pidxA[p] : -1;
                posL[tid] = p;
                pidxL[tid] = pi;
                hasH = (p >= 0) && (pi != -1);
            }
            if (tid < 64) {
                unsigned long long m = __ballot(hasH);
                if (tid == 0) sAnyH = (m != 0ULL);
            }
            __syncthreads();
            const bool skipH = !sAnyH;

            f32x4 a01[2][4], aX[2][2], aH[2][2];
#pragma unroll
            for (int mt = 0; mt < 2; mt++) {
#pragma unroll
                for (int q = 0; q < 4; q++) a01[mt][q] = (f32x4){0.f, 0.f, 0.f, 0.f};
#pragma unroll
                for (int q = 0; q < 2; q++) {
                    aX[mt][q] = (f32x4){0.f, 0.f, 0.f, 0.f};
                    aH[mt][q] = (f32x4){0.f, 0.f, 0.f, 0.f};
                }
            }

            const int cb = panel * 128 + w * 32;
            const int nkc = skipH ? 2 : 4;
            for (int kc = 0; kc < nkc; kc++) {
#pragma unroll
                for (int it = 0; it < 4; it++) {
                    int g = it * 256 + tid;
                    int row = g >> 5, jg = g & 31;
                    int kglob = kc * 256 + jg * 8;
                    bf16x8 v = (bf16x8){0, 0, 0, 0, 0, 0, 0, 0};
                    int p = posL[row];
                    if (p >= 0) {
                        if (kglob < 512) {
                            v = *(const bf16x8*)(E + (size_t)p * DDD + kglob);
                        } else {
                            int k2 = kglob - 512;
                            int pi = pidxL[row];
                            if (pi >= 0) {
                                if (YF32) {
                                    const float* s = (const float*)Yv + (size_t)pi * DDD + k2;
                                    float4 a0 = *(const float4*)s;
                                    float4 a1 = *(const float4*)(s + 4);
                                    v[0] = (short)f2bf(a0.x); v[1] = (short)f2bf(a0.y);
                                    v[2] = (short)f2bf(a0.z); v[3] = (short)f2bf(a0.w);
                                    v[4] = (short)f2bf(a1.x); v[5] = (short)f2bf(a1.y);
                                    v[6] = (short)f2bf(a1.z); v[7] = (short)f2bf(a1.w);
                                } else {
                                    v = *(const bf16x8*)((const u16*)Yv + (size_t)pi * DDD + k2);
                                }
                            } else if (pi <= -2) {
                                const float* s = hidden + (size_t)(-pi - 2) * DDD + k2;
                                float4 a0 = *(const float4*)s;
                                float4 a1 = *(const float4*)(s + 4);
                                v[0] = (short)f2bf(a0.x); v[1] = (short)f2bf(a0.y);
                                v[2] = (short)f2bf(a0.z); v[3] = (short)f2bf(a0.w);
                                v[4] = (short)f2bf(a1.x); v[5] = (short)f2bf(a1.y);
                                v[6] = (short)f2bf(a1.z); v[7] = (short)f2bf(a1.w);
                            }
                        }
                    }
                    *(bf16x8*)(As + row * 256 + ((jg ^ (row & 31)) << 3)) = v;
                }
                __syncthreads();

                const bool xpart = (kc < 2);
#pragma unroll
                for (int s = 0; s < 8; s++) {
                    const int kg = kc * 256 + s * 32;
                    bf16x8 bf[6];
#pragma unroll
                    for (int ct = 0; ct < 6; ct++) {
                        int gate = ct >> 1;
                        int nglob = gate * 512 + cb + ((ct & 1) << 4) + lm;
                        bf[ct] = *(const bf16x8*)(Wstk + (size_t)nglob * 1024 + kg + lq * 8);
                    }
#pragma unroll
                    for (int mt = 0; mt < 2; mt++) {
                        int row = mt * 16 + lm;
                        int jgr = s * 4 + lq;
                        bf16x8 af = *(const bf16x8*)(As + row * 256 + ((jgr ^ (row & 31)) << 3));
                        a01[mt][0] = __builtin_amdgcn_mfma_f32_16x16x32_bf16(af, bf[0], a01[mt][0], 0, 0, 0);
                        a01[mt][1] = __builtin_amdgcn_mfma_f32_16x16x32_bf16(af, bf[1], a01[mt][1], 0, 0, 0);
                        a01[mt][2] = __builtin_amdgcn_mfma_f32_16x16x32_bf16(af, bf[2], a01[mt][2], 0, 0, 0);
                        a01[mt][3] = __builtin_amdgcn_mfma_f32_16x16x32_bf16(af, bf[3], a01[mt][3], 0, 0, 0);
                        if (xpart) {
                            aX[mt][0] = __builtin_amdgcn_mfma_f32_16x16x32_bf16(af, bf[4], aX[mt][0], 0, 0, 0);
                            aX[mt][1] = __builtin_amdgcn_mfma_f32_16x16x32_bf16(af, bf[5], aX[mt][1], 0, 0, 0);
                        } else {
                            aH[mt][0] = __builtin_amdgcn_mfma_f32_16x16x32_bf16(af, bf[4], aH[mt][0], 0, 0, 0);
                            aH[mt][1] = __builtin_amdgcn_mfma_f32_16x16x32_bf16(af, bf[5], aH[mt][1], 0, 0, 0);
                        }
                    }
                }
                __syncthreads();
            }

#pragma unroll
            for (int mt = 0; mt < 2; mt++) {
#pragma unroll
                for (int r = 0; r < 4; r++) {
                    int row = mt * 16 + lq * 4 + r;
                    int p = posL[row];
                    if (p < 0) continue;
                    int pi = pidxL[row];
#pragma unroll
                    for (int ct = 0; ct < 2; ct++) {
                        int cglob = cb + ct * 16 + lm;
                        float rpre = a01[mt][ct][r]     + bi[cglob];
                        float zpre = a01[mt][2 + ct][r] + bi[512 + cglob];
                        float xn   = aX[mt][ct][r]      + bi[1024 + cglob];
                        float hn   = aH[mt][ct][r]      + bhn[cglob];
                        float rg = 1.f / (1.f + __expf(-rpre));
                        float zg = 1.f / (1.f + __expf(-zpre));
                        float targ = xn + rg * hn;
                        float t2 = __expf(-2.f * fabsf(targ));
                        float ng = copysignf((1.f - t2) / (1.f + t2), targ);
                        float hp = 0.f;
                        if (pi >= 0)
                            hp = YF32 ? ((const float*)Yv)[(size_t)pi * DDD + cglob]
                                      : bf2f(((const u16*)Yv)[(size_t)pi * DDD + cglob]);
                        else if (pi <= -2)
                            hp = hidden[(size_t)(-pi - 2) * DDD + cglob];
                        float hnew = (1.f - zg) * ng + zg * hp;
                        if (YF32) ((float*)Yv)[(size_t)p * DDD + cglob] = hnew;
                        else      ((u16*)Yv)[(size_t)p * DDD + cglob] = f2bf(hnew);
                    }
                }
            }
            __syncthreads();
        }
        grid_barrier(bar);
    }

    // final hidden: out[b*512+c] = Y[(255*256+b)*512+c]
    for (int i = blockIdx.x * 256 + tid; i < BBB * DDD; i += NBLK * 256) {
        int b = i >> 9, c = i & 511;
        size_t yi = (size_t)(65280 + b) * DDD + c;
        hid_out[i] = YF32 ? ((const float*)Yv)[yi] : bf2f(((const u16*)Yv)[yi]);
    }
}

extern "C" void kernel_launch(void* const* d_in, const int* in_sizes, int n_in,
                              void* d_out, int out_size, void* d_ws, size_t ws_size,
                              hipStream_t stream)
{
    const float* hidden = (const float*)d_in[0];
    const float* obs    = (const float*)d_in[1];
    const int*   dones  = (const int*)d_in[2];
    const int*   avail  = (const int*)d_in[3];
    const float* Wm     = (const float*)d_in[4];
    const float* bm     = (const float*)d_in[5];
    const float* lns    = (const float*)d_in[6];
    const float* lnb    = (const float*)d_in[7];
    const float* Wi     = (const float*)d_in[8];
    const float* bi     = (const float*)d_in[9];
    const float* Wh     = (const float*)d_in[10];
    const float* bhn    = (const float*)d_in[11];
    const float* Wo     = (const float*)d_in[12];
    const float* bo     = (const float*)d_in[13];
    const float* ln2s   = (const float*)d_in[14];
    const float* ln2b   = (const float*)d_in[15];
    const float* Wa     = (const float*)d_in[16];
    const float* ba     = (const float*)d_in[17];
    float* out = (float*)d_out;

    // workspace layout
    char* w = (char*)d_ws;
    u16* Wstk = (u16*)w;  w += (size_t)1536 * 1024 * 2;
    u16* WmT  = (u16*)w;  w += (size_t)3 * DDD * DDD * 2;
    u16* WoT  = (u16*)w;  w += (size_t)DDD * DDD * 2;
    int* meta = (int*)w;  w += 8192;
    int* counts = meta, *offs = meta + 256, *cursor = meta + 512, *maxd = meta + 768;
    int* bar = meta + 1024;                         // sub[16]@stride32 | master@512 | gen@544
    int* depthA = (int*)w;  w += (size_t)MMM * 4;
    int* pidxA  = (int*)w;  w += (size_t)MMM * 4;
    int* list   = (int*)w;  w += (size_t)MMM * 4;
    u16* P = (u16*)w;       w += (size_t)MMM * DDD * 2;
    void* Yv = (void*)w;
    const size_t base = (size_t)(w - (char*)d_ws);
    const bool yf32 = (ws_size >= base + (size_t)MMM * DDD * 4);

    dim3 tgrid(16, 16);
    for (int l = 0; l < 3; l++)
        transpose_cvt_k<<<tgrid, 256, 0, stream>>>(Wm + (size_t)l * DDD * DDD, WmT + (size_t)l * DDD * DDD, DDD);
    transpose_cvt_k<<<tgrid, 256, 0, stream>>>(Wo, WoT, DDD);
    for (int g = 0; g < 3; g++) {
        transpose_cvt_k<<<tgrid, 256, 0, stream>>>(Wi + (size_t)g * DDD * DDD, Wstk + (size_t)g * 512 * 1024, 1024);
        transpose_cvt_k<<<tgrid, 256, 0, stream>>>(Wh + (size_t)g * DDD * DDD, Wstk + (size_t)g * 512 * 1024 + 512, 1024);
    }
    hipMemsetAsync(meta, 0, 8192, stream);

    depth_build_k<<<1, 256, 0, stream>>>(dones, depthA, pidxA, counts, maxd);
    scan_k<<<1, 64, 0, stream>>>(counts, offs);
    scatter_k<<<MMM / 256, 256, 0, stream>>>(depthA, offs, cursor, list);

    // encoder: obs -> P -> Y -> P
    u16* Yq = (u16*)Yv;
    gemm_bf16_k<true><<<dim3(MMM / 128, 4), 256, 0, stream>>>(obs, WmT, bm, P, DDD);
    ln_relu_k<<<dim3(MMM / 4), 256, 0, stream>>>(P, lns, lnb);
    gemm_bf16_k<false><<<dim3(MMM / 128, 4), 256, 0, stream>>>(P, WmT + (size_t)DDD * DDD, bm + DDD, Yq, DDD);
    ln_relu_k<<<dim3(MMM / 4), 256, 0, stream>>>(Yq, lns + DDD, lnb + DDD);
    gemm_bf16_k<false><<<dim3(MMM / 128, 4), 256, 0, stream>>>(Yq, WmT + (size_t)2 * DDD * DDD, bm + 2 * DDD, P, DDD);
    ln_relu_k<<<dim3(MMM / 4), 256, 0, stream>>>(P, lns + 2 * DDD, lnb + 2 * DDD);

    // persistent-block GRU, fixed 512 blocks (2/CU co-resident)
    if (yf32)
        gru_depth_k<true><<<dim3(NBLK), 256, 0, stream>>>(
            P, hidden, Wstk, bi, bhn, list, offs, counts, maxd, pidxA, Yv, out, bar);
    else
        gru_depth_k<false><<<dim3(NBLK), 256, 0, stream>>>(
            P, hidden, Wstk, bi, bhn, list, offs, counts, maxd, pidxA, Yv, out, bar);

    // head: Y -> P, LN, logits
    if (yf32)
        gemm_bf16_k<true><<<dim3(MMM / 128, 4), 256, 0, stream>>>(Yv, WoT, bo, P, DDD);
    else
        gemm_bf16_k<false><<<dim3(MMM / 128, 4), 256, 0, stream>>>(Yv, WoT, bo, P, DDD);
    ln_relu_k<<<dim3(MMM / 4), 256, 0, stream>>>(P, ln2s, ln2b);
    logits_k<<<dim3(MMM / 8), 256, 0, stream>>>(P, Wa, ba, avail, out + BBB * DDD);
}